// Round 1
// baseline (1575.302 us; speedup 1.0000x reference)
//
#include <hip/hip_runtime.h>
#include <cstdint>

#define TT   1024
#define HH   1024
#define EE   64
#define KK   6
#define GG   8
#define TGn  4
#define FF   512
#define FN   1024   // F*NSH
#define CAPc 384
#define SCALEs 2.5f

// ---------------- gate + grouped top-k routing ----------------
__global__ __launch_bounds__(256) void gate_topk_kernel(
    const float* __restrict__ x, const float* __restrict__ gw,
    const float* __restrict__ bias, int* __restrict__ ids,
    float* __restrict__ tw) {
  __shared__ float xs[HH];
  __shared__ float sc[EE];
  __shared__ float scores[EE];
  const int t = blockIdx.x;
  for (int i = threadIdx.x; i < HH; i += blockDim.x) xs[i] = x[t * HH + i];
  __syncthreads();
  if (threadIdx.x < EE) {
    const int e = threadIdx.x;
    const float* w = gw + e * HH;
    float acc = 0.f;
    for (int i = 0; i < HH; ++i) acc = fmaf(xs[i], w[i], acc);
    float s = 1.f / (1.f + expf(-acc));   // precise exp: selection fidelity
    scores[e] = s;
    sc[e] = s + bias[e];
  }
  __syncthreads();
  if (threadIdx.x == 0) {
    // group scores = sum of top-2 (bias-corrected) per group of 8
    float gs[GG];
    for (int g = 0; g < GG; ++g) {
      float m1 = -1e30f, m2 = -1e30f;
      for (int j = 0; j < EE / GG; ++j) {
        float v = sc[g * (EE / GG) + j];
        if (v > m1) { m2 = m1; m1 = v; }
        else if (v > m2) { m2 = v; }
      }
      gs[g] = m1 + m2;
    }
    unsigned gmask = 0;
    for (int r = 0; r < TGn; ++r) {           // top-4 groups, ties -> low idx
      int best = -1; float bv = -1e30f;
      for (int g = 0; g < GG; ++g)
        if (!((gmask >> g) & 1u) && gs[g] > bv) { bv = gs[g]; best = g; }
      gmask |= 1u << best;
    }
    unsigned long long used = 0ull;
    float wsum = 0.f;
    int idbuf[KK]; float wbuf[KK];
    for (int r = 0; r < KK; ++r) {            // top-6 experts on masked sc
      int best = -1; float bv = -3e38f;
      for (int e = 0; e < EE; ++e) {
        if (!((gmask >> (e / (EE / GG))) & 1u)) continue;
        if ((used >> e) & 1ull) continue;
        float v = sc[e];
        if (v > bv) { bv = v; best = e; }
      }
      used |= 1ull << best;
      idbuf[r] = best;
      wbuf[r] = scores[best];                 // weights from RAW sigmoid scores
      wsum += scores[best];
    }
    const float inv = SCALEs / wsum;
    for (int r = 0; r < KK; ++r) {
      ids[t * KK + r] = idbuf[r];
      tw[t * KK + r] = wbuf[r] * inv;
    }
  }
}

// ---------------- dispatch: per-expert slot assignment ----------------
__global__ void dispatch_kernel(const int* __restrict__ ids,
                                const float* __restrict__ tw,
                                int* __restrict__ counts,
                                int* __restrict__ tok_of,
                                float* __restrict__ wt_of) {
  const int i = blockIdx.x * blockDim.x + threadIdx.x;
  if (i >= TT * KK) return;
  const int e = ids[i];
  const int p = atomicAdd(&counts[e], 1);
  if (p < CAPc) {
    tok_of[e * CAPc + p] = i / KK;
    wt_of[e * CAPc + p] = tw[i];
  }
}

// ---------------- shared experts: GEMM1 + SiLU*mul ----------------
// act_s[t, n] = silu(x@sw13[:, n]) * (x@sw13[:, n+FN]),  n in [0, FN)
__global__ __launch_bounds__(256) void shared_gemm1(
    const float* __restrict__ x, const float* __restrict__ sw13,
    float* __restrict__ act_s) {
  __shared__ float As[16][65];
  __shared__ float B1[16][65];
  __shared__ float B2[16][65];
  const int m0 = blockIdx.y * 64;
  const int n0 = blockIdx.x * 64;
  const int tid = threadIdx.x;
  const int tx = tid & 15, ty = tid >> 4;
  float acc1[4][4] = {}, acc2[4][4] = {};
  for (int k0 = 0; k0 < HH; k0 += 16) {
    for (int l = tid; l < 64 * 16; l += 256) {
      int mm = l >> 4, kk = l & 15;
      As[kk][mm] = x[(m0 + mm) * HH + k0 + kk];
    }
    for (int l = tid; l < 16 * 64; l += 256) {
      int kk = l >> 6, nn = l & 63;
      B1[kk][nn] = sw13[(k0 + kk) * (2 * FN) + n0 + nn];
      B2[kk][nn] = sw13[(k0 + kk) * (2 * FN) + FN + n0 + nn];
    }
    __syncthreads();
#pragma unroll
    for (int kk = 0; kk < 16; ++kk) {
      float a[4], b1[4], b2[4];
#pragma unroll
      for (int i = 0; i < 4; ++i) a[i] = As[kk][ty * 4 + i];
#pragma unroll
      for (int j = 0; j < 4; ++j) { b1[j] = B1[kk][tx * 4 + j]; b2[j] = B2[kk][tx * 4 + j]; }
#pragma unroll
      for (int i = 0; i < 4; ++i)
#pragma unroll
        for (int j = 0; j < 4; ++j) {
          acc1[i][j] = fmaf(a[i], b1[j], acc1[i][j]);
          acc2[i][j] = fmaf(a[i], b2[j], acc2[i][j]);
        }
    }
    __syncthreads();
  }
#pragma unroll
  for (int i = 0; i < 4; ++i)
#pragma unroll
    for (int j = 0; j < 4; ++j) {
      float g = acc1[i][j], u = acc2[i][j];
      float v = (g / (1.f + __expf(-g))) * u;
      act_s[(m0 + ty * 4 + i) * FN + n0 + tx * 4 + j] = v;
    }
}

// ---------------- shared experts: GEMM2 (writes out = shared) ----------------
__global__ __launch_bounds__(256) void shared_gemm2(
    const float* __restrict__ act_s, const float* __restrict__ sw2,
    float* __restrict__ out) {
  __shared__ float As[16][65];
  __shared__ float Bs[16][65];
  const int m0 = blockIdx.y * 64;
  const int n0 = blockIdx.x * 64;
  const int tid = threadIdx.x;
  const int tx = tid & 15, ty = tid >> 4;
  float acc[4][4] = {};
  for (int k0 = 0; k0 < FN; k0 += 16) {
    for (int l = tid; l < 64 * 16; l += 256) {
      int mm = l >> 4, kk = l & 15;
      As[kk][mm] = act_s[(m0 + mm) * FN + k0 + kk];
    }
    for (int l = tid; l < 16 * 64; l += 256) {
      int kk = l >> 6, nn = l & 63;
      Bs[kk][nn] = sw2[(k0 + kk) * HH + n0 + nn];
    }
    __syncthreads();
#pragma unroll
    for (int kk = 0; kk < 16; ++kk) {
      float a[4], b[4];
#pragma unroll
      for (int i = 0; i < 4; ++i) a[i] = As[kk][ty * 4 + i];
#pragma unroll
      for (int j = 0; j < 4; ++j) b[j] = Bs[kk][tx * 4 + j];
#pragma unroll
      for (int i = 0; i < 4; ++i)
#pragma unroll
        for (int j = 0; j < 4; ++j) acc[i][j] = fmaf(a[i], b[j], acc[i][j]);
    }
    __syncthreads();
  }
#pragma unroll
  for (int i = 0; i < 4; ++i)
#pragma unroll
    for (int j = 0; j < 4; ++j)
      out[(m0 + ty * 4 + i) * HH + n0 + tx * 4 + j] = acc[i][j];
}

// ---------------- routed experts: grouped GEMM1 + SiLU*mul ----------------
// act[e, m, f] = silu(X_e @ w13[e][:, f]) * (X_e @ w13[e][:, f+FF]), f in [0,FF)
__global__ __launch_bounds__(256) void expert_gemm1(
    const float* __restrict__ x, const float* __restrict__ w13,
    const int* __restrict__ counts, const int* __restrict__ tok_of,
    float* __restrict__ act) {
  const int e = blockIdx.z;
  const int n_e = min(counts[e], CAPc);
  const int m0 = blockIdx.y * 64;
  if (m0 >= n_e) return;
  const int n0 = blockIdx.x * 64;
  __shared__ int toks[64];
  __shared__ float As[16][65];
  __shared__ float B1[16][65];
  __shared__ float B2[16][65];
  const int tid = threadIdx.x;
  if (tid < 64) toks[tid] = (m0 + tid < n_e) ? tok_of[e * CAPc + m0 + tid] : -1;
  __syncthreads();
  const float* W = w13 + (size_t)e * HH * (2 * FF);
  const int tx = tid & 15, ty = tid >> 4;
  float acc1[4][4] = {}, acc2[4][4] = {};
  for (int k0 = 0; k0 < HH; k0 += 16) {
    for (int l = tid; l < 64 * 16; l += 256) {
      int mm = l >> 4, kk = l & 15;
      int tk = toks[mm];
      As[kk][mm] = (tk >= 0) ? x[tk * HH + k0 + kk] : 0.f;
    }
    for (int l = tid; l < 16 * 64; l += 256) {
      int kk = l >> 6, nn = l & 63;
      B1[kk][nn] = W[(k0 + kk) * (2 * FF) + n0 + nn];
      B2[kk][nn] = W[(k0 + kk) * (2 * FF) + FF + n0 + nn];
    }
    __syncthreads();
#pragma unroll
    for (int kk = 0; kk < 16; ++kk) {
      float a[4], b1[4], b2[4];
#pragma unroll
      for (int i = 0; i < 4; ++i) a[i] = As[kk][ty * 4 + i];
#pragma unroll
      for (int j = 0; j < 4; ++j) { b1[j] = B1[kk][tx * 4 + j]; b2[j] = B2[kk][tx * 4 + j]; }
#pragma unroll
      for (int i = 0; i < 4; ++i)
#pragma unroll
        for (int j = 0; j < 4; ++j) {
          acc1[i][j] = fmaf(a[i], b1[j], acc1[i][j]);
          acc2[i][j] = fmaf(a[i], b2[j], acc2[i][j]);
        }
    }
    __syncthreads();
  }
#pragma unroll
  for (int i = 0; i < 4; ++i)
#pragma unroll
    for (int j = 0; j < 4; ++j) {
      float g = acc1[i][j], u = acc2[i][j];
      float v = (g / (1.f + __expf(-g))) * u;  // padded rows: silu(0)*0 = 0
      act[(size_t)e * CAPc * FF + (size_t)(m0 + ty * 4 + i) * FF + n0 + tx * 4 + j] = v;
    }
}

// ---------------- routed experts: grouped GEMM2 + weighted combine ----------------
__global__ __launch_bounds__(256) void expert_gemm2(
    const float* __restrict__ act, const float* __restrict__ w2,
    const int* __restrict__ counts, const int* __restrict__ tok_of,
    const float* __restrict__ wt_of, float* __restrict__ out) {
  const int e = blockIdx.z;
  const int n_e = min(counts[e], CAPc);
  const int m0 = blockIdx.y * 64;
  if (m0 >= n_e) return;
  const int n0 = blockIdx.x * 64;
  __shared__ int toks[64];
  __shared__ float wts[64];
  __shared__ float As[16][65];
  __shared__ float Bs[16][65];
  const int tid = threadIdx.x;
  if (tid < 64) {
    const bool valid = (m0 + tid < n_e);
    toks[tid] = valid ? tok_of[e * CAPc + m0 + tid] : -1;
    wts[tid]  = valid ? wt_of[e * CAPc + m0 + tid] : 0.f;
  }
  __syncthreads();
  const float* A = act + (size_t)e * CAPc * FF;
  const float* W = w2 + (size_t)e * FF * HH;
  const int tx = tid & 15, ty = tid >> 4;
  float acc[4][4] = {};
  for (int k0 = 0; k0 < FF; k0 += 16) {
    for (int l = tid; l < 64 * 16; l += 256) {
      int mm = l >> 4, kk = l & 15;
      As[kk][mm] = A[(size_t)(m0 + mm) * FF + k0 + kk];
    }
    for (int l = tid; l < 16 * 64; l += 256) {
      int kk = l >> 6, nn = l & 63;
      Bs[kk][nn] = W[(k0 + kk) * HH + n0 + nn];
    }
    __syncthreads();
#pragma unroll
    for (int kk = 0; kk < 16; ++kk) {
      float a[4], b[4];
#pragma unroll
      for (int i = 0; i < 4; ++i) a[i] = As[kk][ty * 4 + i];
#pragma unroll
      for (int j = 0; j < 4; ++j) b[j] = Bs[kk][tx * 4 + j];
#pragma unroll
      for (int i = 0; i < 4; ++i)
#pragma unroll
        for (int j = 0; j < 4; ++j) acc[i][j] = fmaf(a[i], b[j], acc[i][j]);
    }
    __syncthreads();
  }
#pragma unroll
  for (int i = 0; i < 4; ++i) {
    const int mm = ty * 4 + i;
    const int tk = toks[mm];
    if (tk < 0) continue;
    const float wgt = wts[mm];
#pragma unroll
    for (int j = 0; j < 4; ++j)
      atomicAdd(&out[tk * HH + n0 + tx * 4 + j], acc[i][j] * wgt);
  }
}

extern "C" void kernel_launch(void* const* d_in, const int* in_sizes, int n_in,
                              void* d_out, int out_size, void* d_ws, size_t ws_size,
                              hipStream_t stream) {
  const float* x    = (const float*)d_in[0];
  const float* gw   = (const float*)d_in[1];
  const float* bias = (const float*)d_in[2];
  const float* w13  = (const float*)d_in[3];
  const float* w2   = (const float*)d_in[4];
  const float* sw13 = (const float*)d_in[5];
  const float* sw2  = (const float*)d_in[6];
  float* out = (float*)d_out;

  char* ws = (char*)d_ws;
  size_t off = 0;
  int*   counts = (int*)(ws + off);   off += 256;
  int*   tok_of = (int*)(ws + off);   off += (size_t)EE * CAPc * 4;
  float* wt_of  = (float*)(ws + off); off += (size_t)EE * CAPc * 4;
  int*   ids    = (int*)(ws + off);   off += (size_t)TT * KK * 4;
  float* tw     = (float*)(ws + off); off += (size_t)TT * KK * 4;
  off = (off + 255) & ~(size_t)255;
  float* act    = (float*)(ws + off); off += (size_t)EE * CAPc * FF * 4;   // ~50 MB
  float* act_s  = (float*)(ws + off); off += (size_t)TT * FN * 4;          // 4 MB

  hipMemsetAsync(counts, 0, 256, stream);
  gate_topk_kernel<<<TT, 256, 0, stream>>>(x, gw, bias, ids, tw);
  dispatch_kernel<<<(TT * KK + 255) / 256, 256, 0, stream>>>(ids, tw, counts, tok_of, wt_of);
  shared_gemm1<<<dim3(FN / 64, TT / 64), 256, 0, stream>>>(x, sw13, act_s);
  shared_gemm2<<<dim3(HH / 64, TT / 64), 256, 0, stream>>>(act_s, sw2, out);
  expert_gemm1<<<dim3(FF / 64, CAPc / 64, EE), 256, 0, stream>>>(x, w13, counts, tok_of, act);
  expert_gemm2<<<dim3(HH / 64, CAPc / 64, EE), 256, 0, stream>>>(act, w2, counts, tok_of, wt_of, out);
}

// Round 2
// 634.214 us; speedup vs baseline: 2.4839x; 2.4839x over previous
//
#include <hip/hip_runtime.h>
#include <cstdint>

#define TT   1024
#define HH   1024
#define EE   64
#define KK   6
#define GG   8
#define TGn  4
#define FF   512
#define FN   1024   // F*NSH
#define CAPc 384
#define SCALEs 2.5f

typedef unsigned int u32;
typedef unsigned short u16;
typedef short short8 __attribute__((ext_vector_type(8)));
typedef float f32x4 __attribute__((ext_vector_type(4)));
union ABu { uint4 u; short8 s; };

// round-half-up fp32->bf16, two at once, 3 VALU ops total
__device__ __forceinline__ u32 pack_bf16(float a, float b) {
  u32 ua = __float_as_uint(a) + 0x8000u;
  u32 ub = __float_as_uint(b) + 0x8000u;
  return __builtin_amdgcn_perm(ub, ua, 0x07060302u);
}
__device__ __forceinline__ u16 bf16_1(float a) {
  u32 ua = __float_as_uint(a) + 0x8000u;
  return (u16)(ua >> 16);
}

// ---------------- convert x to bf16 (read 6x by routed path) ----------------
__global__ __launch_bounds__(256) void convert_x(const float* __restrict__ x,
                                                 u32* __restrict__ xb) {
  const int i = blockIdx.x * 256 + threadIdx.x;   // 262144 threads, 4 floats each
  float4 v = ((const float4*)x)[i];
  uint2 o;
  o.x = pack_bf16(v.x, v.y);
  o.y = pack_bf16(v.z, v.w);
  ((uint2*)xb)[i] = o;
}

// ---------------- gate + grouped top-k routing ----------------
__global__ __launch_bounds__(256) void gate_topk_kernel(
    const float* __restrict__ x, const float* __restrict__ gw,
    const float* __restrict__ bias, int* __restrict__ ids,
    float* __restrict__ tw) {
  __shared__ float xs[HH];
  __shared__ float part[256];
  __shared__ float sc[EE];
  __shared__ float scores[EE];
  const int t = blockIdx.x, tid = threadIdx.x;
  ((float4*)xs)[tid] = ((const float4*)(x + (size_t)t * HH))[tid];
  __syncthreads();
  {
    const int e = tid & 63, seg = tid >> 6;
    const float* w = gw + (size_t)e * HH + seg * 256;
    const float* xv = xs + seg * 256;
    float acc = 0.f;
#pragma unroll 8
    for (int i = 0; i < 256; ++i) acc = fmaf(xv[i], w[i], acc);
    part[tid] = acc;
  }
  __syncthreads();
  if (tid < 64) {
    float a = part[tid] + part[tid + 64] + part[tid + 128] + part[tid + 192];
    float s = 1.f / (1.f + expf(-a));
    scores[tid] = s;
    sc[tid] = s + bias[tid];
  }
  __syncthreads();
  if (tid == 0) {
    float gs[GG];
    for (int g = 0; g < GG; ++g) {
      float m1 = -1e30f, m2 = -1e30f;
      for (int j = 0; j < EE / GG; ++j) {
        float v = sc[g * (EE / GG) + j];
        if (v > m1) { m2 = m1; m1 = v; }
        else if (v > m2) { m2 = v; }
      }
      gs[g] = m1 + m2;
    }
    unsigned gmask = 0;
    for (int r = 0; r < TGn; ++r) {
      int best = -1; float bv = -1e30f;
      for (int g = 0; g < GG; ++g)
        if (!((gmask >> g) & 1u) && gs[g] > bv) { bv = gs[g]; best = g; }
      gmask |= 1u << best;
    }
    unsigned long long used = 0ull;
    float wsum = 0.f;
    int idbuf[KK]; float wbuf[KK];
    for (int r = 0; r < KK; ++r) {
      int best = -1; float bv = -3e38f;
      for (int e = 0; e < EE; ++e) {
        if (!((gmask >> (e / (EE / GG))) & 1u)) continue;
        if ((used >> e) & 1ull) continue;
        float v = sc[e];
        if (v > bv) { bv = v; best = e; }
      }
      used |= 1ull << best;
      idbuf[r] = best;
      wbuf[r] = scores[best];
      wsum += scores[best];
    }
    const float inv = SCALEs / wsum;
    for (int r = 0; r < KK; ++r) {
      ids[t * KK + r] = idbuf[r];
      tw[t * KK + r] = wbuf[r] * inv;
    }
  }
}

// ---------------- dispatch ----------------
__global__ void dispatch_kernel(const int* __restrict__ ids,
                                const float* __restrict__ tw,
                                int* __restrict__ counts,
                                int* __restrict__ tok_of,
                                float* __restrict__ wt_of) {
  const int i = blockIdx.x * blockDim.x + threadIdx.x;
  if (i >= TT * KK) return;
  const int e = ids[i];
  const int p = atomicAdd(&counts[e], 1);
  if (p < CAPc) {
    tok_of[e * CAPc + p] = i / KK;
    wt_of[e * CAPc + p] = tw[i];
  }
}

// LDS strides (in dwords)
#define LDA 20    // A row: 16 dwords (32 bf16) + 4 pad
#define LDB 132   // B row: 128 dwords + 4 pad

// ---------------- routed experts: GEMM1 + SiLU*mul (MFMA) ----------------
// block: 64 rows x (64 gate + 64 up cols), K=HH
__global__ __launch_bounds__(256) void expert_gemm1(
    const u32* __restrict__ xb, const float* __restrict__ w13,
    const int* __restrict__ counts, const int* __restrict__ tok_of,
    u16* __restrict__ act) {
  const int e = blockIdx.z;
  const int n_e = min(counts[e], CAPc);
  const int m0 = blockIdx.y * 64;
  if (m0 >= n_e) return;
  const int n0 = blockIdx.x * 64;
  __shared__ __align__(16) u32 As[64 * LDA];
  __shared__ __align__(16) u32 Bs[16 * LDB];
  __shared__ int toks[64];
  const int tid = threadIdx.x;
  if (tid < 64) toks[tid] = (m0 + tid < n_e) ? tok_of[e * CAPc + m0 + tid] : -1;
  __syncthreads();
  const int wave = tid >> 6, lane = tid & 63;
  const int quad = lane >> 4, l16 = lane & 15;
  const float* W = w13 + (size_t)e * (HH * 2 * FF);
  const int am = tid >> 2, akd = (tid & 3) << 2;
  const int atok = toks[am];
  const u32* arow = xb + (size_t)(atok < 0 ? 0 : atok) * (HH / 2);
  const int bkd0 = tid >> 5;
  const int bn4 = (tid & 31) << 2;
  const int bcol = (bn4 < 64) ? (n0 + bn4) : (FF + n0 + (bn4 - 64));

  f32x4 accg[4] = {}, accu[4] = {};
  for (int k0 = 0; k0 < HH; k0 += 32) {
    uint4 av = make_uint4(0u, 0u, 0u, 0u);
    if (atok >= 0) av = *(const uint4*)(arow + (k0 >> 1) + akd);
    *(uint4*)(&As[am * LDA + akd]) = av;
#pragma unroll
    for (int i = 0; i < 2; ++i) {
      const int kd = bkd0 + i * 8;
      const float* p = W + (size_t)(k0 + 2 * kd) * (2 * FF) + bcol;
      float4 r0 = *(const float4*)p;
      float4 r1 = *(const float4*)(p + 2 * FF);
      uint4 bv;
      bv.x = pack_bf16(r0.x, r1.x);
      bv.y = pack_bf16(r0.y, r1.y);
      bv.z = pack_bf16(r0.z, r1.z);
      bv.w = pack_bf16(r0.w, r1.w);
      *(uint4*)(&Bs[kd * LDB + bn4]) = bv;
    }
    __syncthreads();
    ABu bg, bu;
    const int cg = wave * 16 + l16;
    bg.u.x = Bs[(quad * 4 + 0) * LDB + cg];
    bg.u.y = Bs[(quad * 4 + 1) * LDB + cg];
    bg.u.z = Bs[(quad * 4 + 2) * LDB + cg];
    bg.u.w = Bs[(quad * 4 + 3) * LDB + cg];
    bu.u.x = Bs[(quad * 4 + 0) * LDB + 64 + cg];
    bu.u.y = Bs[(quad * 4 + 1) * LDB + 64 + cg];
    bu.u.z = Bs[(quad * 4 + 2) * LDB + 64 + cg];
    bu.u.w = Bs[(quad * 4 + 3) * LDB + 64 + cg];
#pragma unroll
    for (int mi = 0; mi < 4; ++mi) {
      ABu a;
      a.u = *(const uint4*)(&As[(mi * 16 + l16) * LDA + quad * 4]);
      accg[mi] = __builtin_amdgcn_mfma_f32_16x16x32_bf16(a.s, bg.s, accg[mi], 0, 0, 0);
      accu[mi] = __builtin_amdgcn_mfma_f32_16x16x32_bf16(a.s, bu.s, accu[mi], 0, 0, 0);
    }
    __syncthreads();
  }
  const int col = n0 + wave * 16 + l16;
#pragma unroll
  for (int mi = 0; mi < 4; ++mi) {
#pragma unroll
    for (int r = 0; r < 4; ++r) {
      const int row = m0 + mi * 16 + quad * 4 + r;
      const float g = accg[mi][r], u = accu[mi][r];
      const float v = (g / (1.f + __expf(-g))) * u;
      act[((size_t)e * CAPc + row) * FF + col] = bf16_1(v);
    }
  }
}

// ---------------- routed experts: GEMM2 + weighted atomic combine (MFMA) ----------------
// block: 64 rows x 128 cols of H, K=FF
__global__ __launch_bounds__(256) void expert_gemm2(
    const u32* __restrict__ act, const float* __restrict__ w2,
    const int* __restrict__ counts, const int* __restrict__ tok_of,
    const float* __restrict__ wt_of, float* __restrict__ out) {
  const int e = blockIdx.z;
  const int n_e = min(counts[e], CAPc);
  const int m0 = blockIdx.y * 64;
  if (m0 >= n_e) return;
  const int n0 = blockIdx.x * 128;
  __shared__ __align__(16) u32 As[64 * LDA];
  __shared__ __align__(16) u32 Bs[16 * LDB];
  __shared__ int toks[64];
  __shared__ float wts[64];
  const int tid = threadIdx.x;
  if (tid < 64) {
    const bool valid = (m0 + tid < n_e);
    toks[tid] = valid ? tok_of[e * CAPc + m0 + tid] : -1;
    wts[tid] = valid ? wt_of[e * CAPc + m0 + tid] : 0.f;
  }
  __syncthreads();
  const int wave = tid >> 6, lane = tid & 63;
  const int quad = lane >> 4, l16 = lane & 15;
  const float* W = w2 + (size_t)e * (FF * HH);
  const int am = tid >> 2, akd = (tid & 3) << 2;
  const bool arow_ok = (m0 + am < n_e);
  const u32* arow = act + ((size_t)e * CAPc + m0 + am) * (FF / 2);
  const int bkd0 = tid >> 5;
  const int bn4 = (tid & 31) << 2;

  f32x4 acc0[4] = {}, acc1[4] = {};
  for (int k0 = 0; k0 < FF; k0 += 32) {
    uint4 av = make_uint4(0u, 0u, 0u, 0u);
    if (arow_ok) av = *(const uint4*)(arow + (k0 >> 1) + akd);
    *(uint4*)(&As[am * LDA + akd]) = av;
#pragma unroll
    for (int i = 0; i < 2; ++i) {
      const int kd = bkd0 + i * 8;
      const float* p = W + (size_t)(k0 + 2 * kd) * HH + n0 + bn4;
      float4 r0 = *(const float4*)p;
      float4 r1 = *(const float4*)(p + HH);
      uint4 bv;
      bv.x = pack_bf16(r0.x, r1.x);
      bv.y = pack_bf16(r0.y, r1.y);
      bv.z = pack_bf16(r0.z, r1.z);
      bv.w = pack_bf16(r0.w, r1.w);
      *(uint4*)(&Bs[kd * LDB + bn4]) = bv;
    }
    __syncthreads();
    ABu b0, b1;
    const int c0 = wave * 32 + l16;
    b0.u.x = Bs[(quad * 4 + 0) * LDB + c0];
    b0.u.y = Bs[(quad * 4 + 1) * LDB + c0];
    b0.u.z = Bs[(quad * 4 + 2) * LDB + c0];
    b0.u.w = Bs[(quad * 4 + 3) * LDB + c0];
    b1.u.x = Bs[(quad * 4 + 0) * LDB + 16 + c0];
    b1.u.y = Bs[(quad * 4 + 1) * LDB + 16 + c0];
    b1.u.z = Bs[(quad * 4 + 2) * LDB + 16 + c0];
    b1.u.w = Bs[(quad * 4 + 3) * LDB + 16 + c0];
#pragma unroll
    for (int mi = 0; mi < 4; ++mi) {
      ABu a;
      a.u = *(const uint4*)(&As[(mi * 16 + l16) * LDA + quad * 4]);
      acc0[mi] = __builtin_amdgcn_mfma_f32_16x16x32_bf16(a.s, b0.s, acc0[mi], 0, 0, 0);
      acc1[mi] = __builtin_amdgcn_mfma_f32_16x16x32_bf16(a.s, b1.s, acc1[mi], 0, 0, 0);
    }
    __syncthreads();
  }
  const int c0 = n0 + wave * 32 + l16;
#pragma unroll
  for (int mi = 0; mi < 4; ++mi) {
#pragma unroll
    for (int r = 0; r < 4; ++r) {
      const int rr = mi * 16 + quad * 4 + r;
      const int tk = toks[rr];
      if (tk < 0) continue;
      const float wt = wts[rr];
      atomicAdd(&out[(size_t)tk * HH + c0], acc0[mi][r] * wt);
      atomicAdd(&out[(size_t)tk * HH + c0 + 16], acc1[mi][r] * wt);
    }
  }
}

// ---------------- shared experts: GEMM1 + SiLU*mul (MFMA) ----------------
__global__ __launch_bounds__(256) void shared_gemm1(
    const u32* __restrict__ xb, const float* __restrict__ sw13,
    u16* __restrict__ act_s) {
  const int m0 = blockIdx.y * 64;
  const int n0 = blockIdx.x * 64;
  __shared__ __align__(16) u32 As[64 * LDA];
  __shared__ __align__(16) u32 Bs[16 * LDB];
  const int tid = threadIdx.x;
  const int wave = tid >> 6, lane = tid & 63;
  const int quad = lane >> 4, l16 = lane & 15;
  const int am = tid >> 2, akd = (tid & 3) << 2;
  const u32* arow = xb + (size_t)(m0 + am) * (HH / 2);
  const int bkd0 = tid >> 5;
  const int bn4 = (tid & 31) << 2;
  const int bcol = (bn4 < 64) ? (n0 + bn4) : (FN + n0 + (bn4 - 64));

  f32x4 accg[4] = {}, accu[4] = {};
  for (int k0 = 0; k0 < HH; k0 += 32) {
    uint4 av = *(const uint4*)(arow + (k0 >> 1) + akd);
    *(uint4*)(&As[am * LDA + akd]) = av;
#pragma unroll
    for (int i = 0; i < 2; ++i) {
      const int kd = bkd0 + i * 8;
      const float* p = sw13 + (size_t)(k0 + 2 * kd) * (2 * FN) + bcol;
      float4 r0 = *(const float4*)p;
      float4 r1 = *(const float4*)(p + 2 * FN);
      uint4 bv;
      bv.x = pack_bf16(r0.x, r1.x);
      bv.y = pack_bf16(r0.y, r1.y);
      bv.z = pack_bf16(r0.z, r1.z);
      bv.w = pack_bf16(r0.w, r1.w);
      *(uint4*)(&Bs[kd * LDB + bn4]) = bv;
    }
    __syncthreads();
    ABu bg, bu;
    const int cg = wave * 16 + l16;
    bg.u.x = Bs[(quad * 4 + 0) * LDB + cg];
    bg.u.y = Bs[(quad * 4 + 1) * LDB + cg];
    bg.u.z = Bs[(quad * 4 + 2) * LDB + cg];
    bg.u.w = Bs[(quad * 4 + 3) * LDB + cg];
    bu.u.x = Bs[(quad * 4 + 0) * LDB + 64 + cg];
    bu.u.y = Bs[(quad * 4 + 1) * LDB + 64 + cg];
    bu.u.z = Bs[(quad * 4 + 2) * LDB + 64 + cg];
    bu.u.w = Bs[(quad * 4 + 3) * LDB + 64 + cg];
#pragma unroll
    for (int mi = 0; mi < 4; ++mi) {
      ABu a;
      a.u = *(const uint4*)(&As[(mi * 16 + l16) * LDA + quad * 4]);
      accg[mi] = __builtin_amdgcn_mfma_f32_16x16x32_bf16(a.s, bg.s, accg[mi], 0, 0, 0);
      accu[mi] = __builtin_amdgcn_mfma_f32_16x16x32_bf16(a.s, bu.s, accu[mi], 0, 0, 0);
    }
    __syncthreads();
  }
  const int col = n0 + wave * 16 + l16;
#pragma unroll
  for (int mi = 0; mi < 4; ++mi) {
#pragma unroll
    for (int r = 0; r < 4; ++r) {
      const int row = m0 + mi * 16 + quad * 4 + r;
      const float g = accg[mi][r], u = accu[mi][r];
      const float v = (g / (1.f + __expf(-g))) * u;
      act_s[(size_t)row * FN + col] = bf16_1(v);
    }
  }
}

// ---------------- shared experts: GEMM2 (writes out) ----------------
__global__ __launch_bounds__(256) void shared_gemm2(
    const u32* __restrict__ act_s, const float* __restrict__ sw2,
    float* __restrict__ out) {
  const int m0 = blockIdx.y * 64;
  const int n0 = blockIdx.x * 128;
  __shared__ __align__(16) u32 As[64 * LDA];
  __shared__ __align__(16) u32 Bs[16 * LDB];
  const int tid = threadIdx.x;
  const int wave = tid >> 6, lane = tid & 63;
  const int quad = lane >> 4, l16 = lane & 15;
  const int am = tid >> 2, akd = (tid & 3) << 2;
  const u32* arow = act_s + (size_t)(m0 + am) * (FN / 2);
  const int bkd0 = tid >> 5;
  const int bn4 = (tid & 31) << 2;

  f32x4 acc0[4] = {}, acc1[4] = {};
  for (int k0 = 0; k0 < FN; k0 += 32) {
    uint4 av = *(const uint4*)(arow + (k0 >> 1) + akd);
    *(uint4*)(&As[am * LDA + akd]) = av;
#pragma unroll
    for (int i = 0; i < 2; ++i) {
      const int kd = bkd0 + i * 8;
      const float* p = sw2 + (size_t)(k0 + 2 * kd) * HH + n0 + bn4;
      float4 r0 = *(const float4*)p;
      float4 r1 = *(const float4*)(p + HH);
      uint4 bv;
      bv.x = pack_bf16(r0.x, r1.x);
      bv.y = pack_bf16(r0.y, r1.y);
      bv.z = pack_bf16(r0.z, r1.z);
      bv.w = pack_bf16(r0.w, r1.w);
      *(uint4*)(&Bs[kd * LDB + bn4]) = bv;
    }
    __syncthreads();
    ABu b0, b1;
    const int c0 = wave * 32 + l16;
    b0.u.x = Bs[(quad * 4 + 0) * LDB + c0];
    b0.u.y = Bs[(quad * 4 + 1) * LDB + c0];
    b0.u.z = Bs[(quad * 4 + 2) * LDB + c0];
    b0.u.w = Bs[(quad * 4 + 3) * LDB + c0];
    b1.u.x = Bs[(quad * 4 + 0) * LDB + 16 + c0];
    b1.u.y = Bs[(quad * 4 + 1) * LDB + 16 + c0];
    b1.u.z = Bs[(quad * 4 + 2) * LDB + 16 + c0];
    b1.u.w = Bs[(quad * 4 + 3) * LDB + 16 + c0];
#pragma unroll
    for (int mi = 0; mi < 4; ++mi) {
      ABu a;
      a.u = *(const uint4*)(&As[(mi * 16 + l16) * LDA + quad * 4]);
      acc0[mi] = __builtin_amdgcn_mfma_f32_16x16x32_bf16(a.s, b0.s, acc0[mi], 0, 0, 0);
      acc1[mi] = __builtin_amdgcn_mfma_f32_16x16x32_bf16(a.s, b1.s, acc1[mi], 0, 0, 0);
    }
    __syncthreads();
  }
  const int c0 = n0 + wave * 32 + l16;
#pragma unroll
  for (int mi = 0; mi < 4; ++mi) {
#pragma unroll
    for (int r = 0; r < 4; ++r) {
      const int row = m0 + mi * 16 + quad * 4 + r;
      out[(size_t)row * HH + c0] = acc0[mi][r];
      out[(size_t)row * HH + c0 + 16] = acc1[mi][r];
    }
  }
}

extern "C" void kernel_launch(void* const* d_in, const int* in_sizes, int n_in,
                              void* d_out, int out_size, void* d_ws, size_t ws_size,
                              hipStream_t stream) {
  const float* x    = (const float*)d_in[0];
  const float* gw   = (const float*)d_in[1];
  const float* bias = (const float*)d_in[2];
  const float* w13  = (const float*)d_in[3];
  const float* w2   = (const float*)d_in[4];
  const float* sw13 = (const float*)d_in[5];
  const float* sw2  = (const float*)d_in[6];
  float* out = (float*)d_out;

  char* ws = (char*)d_ws;
  size_t off = 0;
  int*   counts = (int*)(ws + off);   off += 256;
  int*   tok_of = (int*)(ws + off);   off += (size_t)EE * CAPc * 4;
  float* wt_of  = (float*)(ws + off); off += (size_t)EE * CAPc * 4;
  int*   ids    = (int*)(ws + off);   off += (size_t)TT * KK * 4;
  float* tw     = (float*)(ws + off); off += (size_t)TT * KK * 4;
  off = (off + 255) & ~(size_t)255;
  u32*   xb     = (u32*)(ws + off);   off += (size_t)TT * HH * 2;        // 2 MB bf16
  u16*   act    = (u16*)(ws + off);   off += (size_t)EE * CAPc * FF * 2; // 25 MB bf16
  u16*   act_s  = (u16*)(ws + off);   off += (size_t)TT * FN * 2;        // 2 MB bf16

  hipMemsetAsync(counts, 0, 256, stream);
  convert_x<<<TT * HH / 1024, 256, 0, stream>>>(x, xb);
  gate_topk_kernel<<<TT, 256, 0, stream>>>(x, gw, bias, ids, tw);
  dispatch_kernel<<<(TT * KK + 255) / 256, 256, 0, stream>>>(ids, tw, counts, tok_of, wt_of);
  shared_gemm1<<<dim3(FN / 64, TT / 64), 256, 0, stream>>>(xb, sw13, act_s);
  shared_gemm2<<<dim3(HH / 128, TT / 64), 256, 0, stream>>>((const u32*)act_s, sw2, out);
  expert_gemm1<<<dim3(FF / 64, CAPc / 64, EE), 256, 0, stream>>>(xb, w13, counts, tok_of, act);
  expert_gemm2<<<dim3(HH / 128, CAPc / 64, EE), 256, 0, stream>>>((const u32*)act, w2, counts, tok_of, wt_of, out);
}

// Round 3
// 632.990 us; speedup vs baseline: 2.4887x; 1.0019x over previous
//
#include <hip/hip_runtime.h>
#include <cstdint>

#define TT   1024
#define HH   1024
#define EE   64
#define KK   6
#define GG   8
#define TGn  4
#define FF   512
#define FN   1024   // F*NSH
#define CAPc 384
#define SCALEs 2.5f

typedef unsigned int u32;
typedef unsigned short u16;
typedef short short8 __attribute__((ext_vector_type(8)));
typedef float f32x4 __attribute__((ext_vector_type(4)));
union ABu { uint4 u; short8 s; };

// round-half-up fp32->bf16, two at once
__device__ __forceinline__ u32 pack_bf16(float a, float b) {
  u32 ua = __float_as_uint(a) + 0x8000u;
  u32 ub = __float_as_uint(b) + 0x8000u;
  return __builtin_amdgcn_perm(ub, ua, 0x07060302u);
}
__device__ __forceinline__ u16 bf16_1(float a) {
  return (u16)((__float_as_uint(a) + 0x8000u) >> 16);
}
__device__ __forceinline__ float bf2f(u32 lo16) {
  return __uint_as_float(lo16 << 16);
}

// ---------------- convert x to bf16 ----------------
__global__ __launch_bounds__(256) void convert_x(const float* __restrict__ x,
                                                 u32* __restrict__ xb) {
  const int i = blockIdx.x * 256 + threadIdx.x;
  float4 v = ((const float4*)x)[i];
  uint2 o;
  o.x = pack_bf16(v.x, v.y);
  o.y = pack_bf16(v.z, v.w);
  ((uint2*)xb)[i] = o;
}

// ---------------- gate + grouped top-k routing ----------------
__global__ __launch_bounds__(256) void gate_topk_kernel(
    const float* __restrict__ x, const float* __restrict__ gw,
    const float* __restrict__ bias, int* __restrict__ ids,
    float* __restrict__ tw) {
  __shared__ float xs[HH];
  __shared__ float part[256];
  __shared__ float sc[EE];
  __shared__ float scores[EE];
  const int t = blockIdx.x, tid = threadIdx.x;
  ((float4*)xs)[tid] = ((const float4*)(x + (size_t)t * HH))[tid];
  __syncthreads();
  {
    const int e = tid & 63, seg = tid >> 6;
    const float* w = gw + (size_t)e * HH + seg * 256;
    const float* xv = xs + seg * 256;
    float acc = 0.f;
#pragma unroll 8
    for (int i = 0; i < 256; ++i) acc = fmaf(xv[i], w[i], acc);
    part[tid] = acc;
  }
  __syncthreads();
  if (tid < 64) {
    float a = part[tid] + part[tid + 64] + part[tid + 128] + part[tid + 192];
    float s = 1.f / (1.f + expf(-a));
    scores[tid] = s;
    sc[tid] = s + bias[tid];
  }
  __syncthreads();
  if (tid == 0) {
    float gs[GG];
    for (int g = 0; g < GG; ++g) {
      float m1 = -1e30f, m2 = -1e30f;
      for (int j = 0; j < EE / GG; ++j) {
        float v = sc[g * (EE / GG) + j];
        if (v > m1) { m2 = m1; m1 = v; }
        else if (v > m2) { m2 = v; }
      }
      gs[g] = m1 + m2;
    }
    unsigned gmask = 0;
    for (int r = 0; r < TGn; ++r) {
      int best = -1; float bv = -1e30f;
      for (int g = 0; g < GG; ++g)
        if (!((gmask >> g) & 1u) && gs[g] > bv) { bv = gs[g]; best = g; }
      gmask |= 1u << best;
    }
    unsigned long long used = 0ull;
    float wsum = 0.f;
    int idbuf[KK]; float wbuf[KK];
    for (int r = 0; r < KK; ++r) {
      int best = -1; float bv = -3e38f;
      for (int e = 0; e < EE; ++e) {
        if (!((gmask >> (e / (EE / GG))) & 1u)) continue;
        if ((used >> e) & 1ull) continue;
        float v = sc[e];
        if (v > bv) { bv = v; best = e; }
      }
      used |= 1ull << best;
      idbuf[r] = best;
      wbuf[r] = scores[best];
      wsum += scores[best];
    }
    const float inv = SCALEs / wsum;
    for (int r = 0; r < KK; ++r) {
      ids[t * KK + r] = idbuf[r];
      tw[t * KK + r] = wbuf[r] * inv;
    }
  }
}

// ---------------- dispatch ----------------
__global__ void dispatch_kernel(const int* __restrict__ ids,
                                int* __restrict__ counts,
                                int* __restrict__ tok_of,
                                int* __restrict__ slot_of) {
  const int i = blockIdx.x * blockDim.x + threadIdx.x;
  if (i >= TT * KK) return;
  const int e = ids[i];
  const int p = atomicAdd(&counts[e], 1);
  slot_of[i] = p;
  if (p < CAPc) tok_of[e * CAPc + p] = i / KK;
}

// LDS strides (dwords)
#define SA 20
#define SB 132

// ================= GEMM1: act = silu(X@W[:, :FH]) * (X@W[:, FH:]) ===========
// block tile MT x (64 gate + 64 up).  2x2 waves; wave = MT/2 rows x (32g+32u).
template<int MT, int FH, bool ROUTED>
__global__ __launch_bounds__(256) void gemm1_k(
    const u32* __restrict__ xb, const float* __restrict__ wsrc,
    const int* __restrict__ counts, const int* __restrict__ tok_of,
    u16* __restrict__ actp) {
  constexpr int WROW = 2 * FH;
  constexpr int RT = MT / 32;
  constexpr int ADW = MT * 16 / 256;      // A dwords staged per thread
  const int e = ROUTED ? blockIdx.z : 0;
  int n_e = MT;
  if (ROUTED) {
    n_e = min(counts[e], CAPc);
    if ((int)(blockIdx.y * MT) >= n_e) return;
  }
  const int m0 = blockIdx.y * MT;
  const int n0 = blockIdx.x * 64;
  __shared__ __align__(16) u32 As[MT * SA];
  __shared__ __align__(16) u32 Bs[16 * SB];
  __shared__ int toks[MT];
  const int tid = threadIdx.x;
  if (ROUTED) {
    for (int i = tid; i < MT; i += 256)
      toks[i] = (m0 + i < n_e) ? tok_of[e * CAPc + m0 + i] : -1;
    __syncthreads();
  }
  const int wave = tid >> 6, lane = tid & 63, quad = lane >> 4, l16 = lane & 15;
  const int ww = wave & 1, wr = wave >> 1;
  const float* W = wsrc + (ROUTED ? (size_t)e * HH * WROW : 0);
  const int arow_i = tid & (MT - 1);
  const int akd = (MT == 128 ? (tid >> 7) : (tid >> 6)) * ADW;
  bool aok = true;
  const u32* arow;
  if (ROUTED) {
    int tk = toks[arow_i];
    aok = tk >= 0;
    arow = xb + (size_t)(aok ? tk : 0) * (HH / 2);
  } else {
    arow = xb + (size_t)(m0 + arow_i) * (HH / 2);
  }
  const int bkd0 = tid >> 5, bn4 = (tid & 31) << 2;
  const int bcol = (bn4 < 64) ? (n0 + bn4) : (FH + n0 + (bn4 - 64));

  uint4 apf[ADW / 4];
  float4 bpf[2][2];
  auto prefetch = [&](int k0) {
#pragma unroll
    for (int i = 0; i < ADW / 4; ++i) {
      uint4 v = *(const uint4*)(arow + (k0 >> 1) + akd + 4 * i);
      if (!aok) v = make_uint4(0u, 0u, 0u, 0u);
      apf[i] = v;
    }
#pragma unroll
    for (int i = 0; i < 2; ++i) {
      const float* p = W + (size_t)(k0 + 2 * (bkd0 + 8 * i)) * WROW + bcol;
      bpf[i][0] = *(const float4*)p;
      bpf[i][1] = *(const float4*)(p + WROW);
    }
  };
  prefetch(0);
  f32x4 acc[RT][4] = {};
  for (int k0 = 0; k0 < HH; k0 += 32) {
    __syncthreads();
#pragma unroll
    for (int i = 0; i < ADW / 4; ++i)
      *(uint4*)(&As[arow_i * SA + akd + 4 * i]) = apf[i];
#pragma unroll
    for (int i = 0; i < 2; ++i) {
      uint4 bv;
      bv.x = pack_bf16(bpf[i][0].x, bpf[i][1].x);
      bv.y = pack_bf16(bpf[i][0].y, bpf[i][1].y);
      bv.z = pack_bf16(bpf[i][0].z, bpf[i][1].z);
      bv.w = pack_bf16(bpf[i][0].w, bpf[i][1].w);
      *(uint4*)(&Bs[(bkd0 + 8 * i) * SB + bn4]) = bv;
    }
    __syncthreads();
    if (k0 + 32 < HH) prefetch(k0 + 32);
    ABu bfr[4];
#pragma unroll
    for (int j = 0; j < 4; ++j) {
      const int cb = (j < 2) ? (ww * 32 + j * 16) : (64 + ww * 32 + (j - 2) * 16);
      const int col = cb + l16;
      bfr[j].u.x = Bs[(quad * 4 + 0) * SB + col];
      bfr[j].u.y = Bs[(quad * 4 + 1) * SB + col];
      bfr[j].u.z = Bs[(quad * 4 + 2) * SB + col];
      bfr[j].u.w = Bs[(quad * 4 + 3) * SB + col];
    }
#pragma unroll
    for (int mi = 0; mi < RT; ++mi) {
      ABu a;
      a.u = *(const uint4*)(&As[(wr * (MT / 2) + mi * 16 + l16) * SA + quad * 4]);
#pragma unroll
      for (int j = 0; j < 4; ++j)
        acc[mi][j] = __builtin_amdgcn_mfma_f32_16x16x32_bf16(a.s, bfr[j].s, acc[mi][j], 0, 0, 0);
    }
  }
#pragma unroll
  for (int mi = 0; mi < RT; ++mi) {
#pragma unroll
    for (int j = 0; j < 2; ++j) {
      const int col = n0 + ww * 32 + j * 16 + l16;
#pragma unroll
      for (int r = 0; r < 4; ++r) {
        const int row = m0 + wr * (MT / 2) + mi * 16 + quad * 4 + r;
        const float g = acc[mi][j][r], u = acc[mi][j + 2][r];
        const float v = (g / (1.f + __expf(-g))) * u;
        size_t idx = ROUTED ? (((size_t)e * CAPc + row) * FH + col)
                            : ((size_t)row * FH + col);
        actp[idx] = bf16_1(v);
      }
    }
  }
}

// ================= GEMM2: out = A @ W  (A bf16 [rows][KD], W fp32 [KD][HH]) ==
// block tile MT x 128.  routed -> bf16 eo[e][slot][H]; shared -> fp32 out.
template<int MT, int KD, bool ROUTED>
__global__ __launch_bounds__(256) void gemm2_k(
    const u32* __restrict__ asrc0, const float* __restrict__ wsrc,
    const int* __restrict__ counts, void* __restrict__ outp) {
  constexpr int RT = MT / 32;
  constexpr int ADW = MT * 16 / 256;
  const int e = ROUTED ? blockIdx.z : 0;
  if (ROUTED) {
    if ((int)(blockIdx.y * MT) >= min(counts[e], CAPc)) return;
  }
  const int m0 = blockIdx.y * MT;
  const int n0 = blockIdx.x * 128;
  __shared__ __align__(16) u32 As[MT * SA];
  __shared__ __align__(16) u32 Bs[16 * SB];
  const int tid = threadIdx.x;
  const int wave = tid >> 6, lane = tid & 63, quad = lane >> 4, l16 = lane & 15;
  const int ww = wave & 1, wr = wave >> 1;
  const float* W = wsrc + (ROUTED ? (size_t)e * KD * HH : 0);
  const int arow_i = tid & (MT - 1);
  const int akd = (MT == 128 ? (tid >> 7) : (tid >> 6)) * ADW;
  const u32* arow = asrc0 + (ROUTED ? ((size_t)e * CAPc + m0 + arow_i) * (KD / 2)
                                    : (size_t)(m0 + arow_i) * (KD / 2));
  const int bkd0 = tid >> 5, bn4 = (tid & 31) << 2;

  uint4 apf[ADW / 4];
  float4 bpf[2][2];
  auto prefetch = [&](int k0) {
#pragma unroll
    for (int i = 0; i < ADW / 4; ++i)
      apf[i] = *(const uint4*)(arow + (k0 >> 1) + akd + 4 * i);
#pragma unroll
    for (int i = 0; i < 2; ++i) {
      const float* p = W + (size_t)(k0 + 2 * (bkd0 + 8 * i)) * HH + n0 + bn4;
      bpf[i][0] = *(const float4*)p;
      bpf[i][1] = *(const float4*)(p + HH);
    }
  };
  prefetch(0);
  f32x4 acc[RT][4] = {};
  for (int k0 = 0; k0 < KD; k0 += 32) {
    __syncthreads();
#pragma unroll
    for (int i = 0; i < ADW / 4; ++i)
      *(uint4*)(&As[arow_i * SA + akd + 4 * i]) = apf[i];
#pragma unroll
    for (int i = 0; i < 2; ++i) {
      uint4 bv;
      bv.x = pack_bf16(bpf[i][0].x, bpf[i][1].x);
      bv.y = pack_bf16(bpf[i][0].y, bpf[i][1].y);
      bv.z = pack_bf16(bpf[i][0].z, bpf[i][1].z);
      bv.w = pack_bf16(bpf[i][0].w, bpf[i][1].w);
      *(uint4*)(&Bs[(bkd0 + 8 * i) * SB + bn4]) = bv;
    }
    __syncthreads();
    if (k0 + 32 < KD) prefetch(k0 + 32);
    ABu bfr[4];
#pragma unroll
    for (int j = 0; j < 4; ++j) {
      const int col = ww * 64 + j * 16 + l16;
      bfr[j].u.x = Bs[(quad * 4 + 0) * SB + col];
      bfr[j].u.y = Bs[(quad * 4 + 1) * SB + col];
      bfr[j].u.z = Bs[(quad * 4 + 2) * SB + col];
      bfr[j].u.w = Bs[(quad * 4 + 3) * SB + col];
    }
#pragma unroll
    for (int mi = 0; mi < RT; ++mi) {
      ABu a;
      a.u = *(const uint4*)(&As[(wr * (MT / 2) + mi * 16 + l16) * SA + quad * 4]);
#pragma unroll
      for (int j = 0; j < 4; ++j)
        acc[mi][j] = __builtin_amdgcn_mfma_f32_16x16x32_bf16(a.s, bfr[j].s, acc[mi][j], 0, 0, 0);
    }
  }
#pragma unroll
  for (int mi = 0; mi < RT; ++mi) {
#pragma unroll
    for (int j = 0; j < 4; ++j) {
      const int col = n0 + ww * 64 + j * 16 + l16;
#pragma unroll
      for (int r = 0; r < 4; ++r) {
        const int row = m0 + wr * (MT / 2) + mi * 16 + quad * 4 + r;
        if (ROUTED) {
          ((u16*)outp)[((size_t)e * CAPc + row) * HH + col] = bf16_1(acc[mi][j][r]);
        } else {
          ((float*)outp)[(size_t)row * HH + col] = acc[mi][j][r];
        }
      }
    }
  }
}

// ---------------- combine: out[t] += sum_k w_k * eo[e_k][slot_k] ------------
__global__ __launch_bounds__(256) void combine_k(
    const u16* __restrict__ eo, const int* __restrict__ ids,
    const int* __restrict__ slot_of, const float* __restrict__ tw,
    float* __restrict__ out) {
  const int t = blockIdx.x, tid = threadIdx.x;
  __shared__ int se[KK];
  __shared__ int ssl[KK];
  __shared__ float swt[KK];
  if (tid < KK) {
    se[tid] = ids[t * KK + tid];
    ssl[tid] = slot_of[t * KK + tid];
    swt[tid] = tw[t * KK + tid];
  }
  __syncthreads();
  const int h = tid * 4;
  float4 o = *(float4*)(&out[(size_t)t * HH + h]);
#pragma unroll
  for (int k = 0; k < KK; ++k) {
    if (ssl[k] >= CAPc) continue;
    const float wgt = swt[k];
    const u16* p = eo + ((size_t)se[k] * CAPc + ssl[k]) * HH + h;
    uint2 v = *(const uint2*)p;
    o.x = fmaf(wgt, bf2f(v.x & 0xffffu), o.x);
    o.y = fmaf(wgt, bf2f(v.x >> 16), o.y);
    o.z = fmaf(wgt, bf2f(v.y & 0xffffu), o.z);
    o.w = fmaf(wgt, bf2f(v.y >> 16), o.w);
  }
  *(float4*)(&out[(size_t)t * HH + h]) = o;
}

extern "C" void kernel_launch(void* const* d_in, const int* in_sizes, int n_in,
                              void* d_out, int out_size, void* d_ws, size_t ws_size,
                              hipStream_t stream) {
  const float* x    = (const float*)d_in[0];
  const float* gw   = (const float*)d_in[1];
  const float* bias = (const float*)d_in[2];
  const float* w13  = (const float*)d_in[3];
  const float* w2   = (const float*)d_in[4];
  const float* sw13 = (const float*)d_in[5];
  const float* sw2  = (const float*)d_in[6];
  float* out = (float*)d_out;

  char* ws = (char*)d_ws;
  size_t off = 0;
  int*   counts  = (int*)(ws + off);   off += 256;
  int*   tok_of  = (int*)(ws + off);   off += (size_t)EE * CAPc * 4;
  int*   ids     = (int*)(ws + off);   off += (size_t)TT * KK * 4;
  int*   slot_of = (int*)(ws + off);   off += (size_t)TT * KK * 4;
  float* tw      = (float*)(ws + off); off += (size_t)TT * KK * 4;
  off = (off + 255) & ~(size_t)255;
  u32*   xb      = (u32*)(ws + off);   off += (size_t)TT * HH * 2;         // 2 MB
  u16*   act     = (u16*)(ws + off);   off += (size_t)EE * CAPc * FF * 2;  // 25 MB
  u16*   eo      = (u16*)(ws + off);   off += (size_t)EE * CAPc * HH * 2;  // 50 MB
  u16*   act_s   = (u16*)(ws + off);   off += (size_t)TT * FN * 2;         // 2 MB

  hipMemsetAsync(counts, 0, 256, stream);
  convert_x<<<TT * HH / 1024, 256, 0, stream>>>(x, xb);
  gate_topk_kernel<<<TT, 256, 0, stream>>>(x, gw, bias, ids, tw);
  dispatch_kernel<<<(TT * KK + 255) / 256, 256, 0, stream>>>(ids, counts, tok_of, slot_of);
  // routed experts
  gemm1_k<128, FF, true><<<dim3(FF / 64, CAPc / 128, EE), 256, 0, stream>>>(
      xb, w13, counts, tok_of, act);
  gemm2_k<128, FF, true><<<dim3(HH / 128, CAPc / 128, EE), 256, 0, stream>>>(
      (const u32*)act, w2, counts, eo);
  // shared experts
  gemm1_k<64, FN, false><<<dim3(FN / 64, TT / 64), 256, 0, stream>>>(
      xb, sw13, nullptr, nullptr, act_s);
  gemm2_k<64, FN, false><<<dim3(HH / 128, TT / 64), 256, 0, stream>>>(
      (const u32*)act_s, sw2, nullptr, out);
  // combine
  combine_k<<<TT, 256, 0, stream>>>(eo, ids, slot_of, tw, out);
}